// Round 10
// baseline (239.803 us; speedup 1.0000x reference)
//
#include <hip/hip_runtime.h>
#include <math.h>

#define N_TOK 16384
#define D_MODEL 2048
#define N_EXP 64
#define CAPACITY 640
#define NREP 8
#define NSTEP 64  // K steps of 32

typedef __attribute__((ext_vector_type(8))) _Float16 h8;
typedef __attribute__((ext_vector_type(4))) float f4;

#define AS1 __attribute__((address_space(1)))
#define AS3 __attribute__((address_space(3)))
__device__ __forceinline__ void gld16(const void* g, void* l) {
  __builtin_amdgcn_global_load_lds((const AS1 void*)g, (AS3 void*)l, 16, 0, 0);
}

// ---------------- K0: W -> B-frag 1KB chunks, fp16 hi/lo (W' = W*2^10) ------
// chunk c = s*8 + part*4 + nt  (s = k/32, part: 0=hi 1=lo, nt = expert/16).
// lane l of chunk c: e = nt*16 + (l&15), k = s*32 + (l>>4)*8, 8 halves.
__global__ __launch_bounds__(256) void k0_cvtw(const float* __restrict__ W,
                                               _Float16* __restrict__ WT) {
  const int lane = threadIdx.x & 63;
  const int c = blockIdx.x * 4 + (threadIdx.x >> 6);  // 0..511
  const int s = c >> 3, q = c & 7;
  const int part = q >> 2, nt = q & 3;
  const int e = nt * 16 + (lane & 15);
  const int k = s * 32 + (lane >> 4) * 8;
  const float* src = W + (size_t)e * D_MODEL + k;
  const float4 a = *(const float4*)src;
  const float4 b = *(const float4*)(src + 4);
  const float f[8] = {a.x, a.y, a.z, a.w, b.x, b.y, b.z, b.w};
  h8 out;
#pragma unroll
  for (int j = 0; j < 8; j++) {
    const float sc = f[j] * 1024.f;
    const _Float16 h = (_Float16)sc;
    out[j] = part ? (_Float16)((sc - (float)h) * 1024.f) : h;
  }
  *(h8*)(WT + (size_t)c * 512 + lane * 8) = out;
}

// ---------------- K12: barrier-free vmcnt ring GEMM, 2 waves/SIMD -----------
// 1024 blocks x 128 thr (2 waves); block = 16 tokens. Wave w = 16 tok x 32 exp
// (experts w*32..w*32+31), fully self-contained: private 3-slot LDS ring
// (6 KB/slot: x 2KB + W 4KB), 6 gld16/step, 2-step lead, vmcnt(12) waits,
// ZERO K-loop barriers. 36 KB/block -> 4 blocks/CU = 8 waves/CU = 2/SIMD:
// co-resident waves interleave the exposed load-completion latency (m114).
__global__ __launch_bounds__(128, 2) void k12_gemm_softmax(
    const float* __restrict__ x, const _Float16* __restrict__ WT,
    float* __restrict__ rw_out, int2* __restrict__ top12,
    float2* __restrict__ wts, int* __restrict__ histR,
    float* __restrict__ zR) {
  __shared__ __align__(16) char LB[36864];  // 2 waves x 3 slots x 6 KB

  const int t = threadIdx.x;
  const int lane = t & 63;
  const int w = t >> 6;
  const int m0 = blockIdx.x * 16;
  const int rep = blockIdx.x & (NREP - 1);

  char* ring = LB + w * 18432;
#define XRs(slot) ((float*)(ring + (slot) * 6144))
#define WRs(slot) ((_Float16*)(ring + (slot) * 6144 + 2048))

  // per-lane sources in fragment layout
  const float* xb = x + (size_t)(m0 + (lane & 15)) * D_MODEL + (lane >> 4) * 8;
  const _Float16* wb = WT + lane * 8;

  f4 acc1[2], acc2[2];
#pragma unroll
  for (int i = 0; i < 2; i++) {
    acc1[i] = (f4)(0.f);
    acc2[i] = (f4)(0.f);
  }

#define STAGE(slot, s)                                              \
  {                                                                 \
    gld16(xb + (s) * 32, XRs(slot));                                \
    gld16(xb + (s) * 32 + 4, XRs(slot) + 256);                      \
    gld16(wb + (size_t)(s) * 4096 + (2 * w + 0) * 512, WRs(slot));  \
    gld16(wb + (size_t)(s) * 4096 + (2 * w + 1) * 512,              \
          WRs(slot) + 512);                                         \
    gld16(wb + (size_t)(s) * 4096 + (4 + 2 * w + 0) * 512,          \
          WRs(slot) + 1024);                                        \
    gld16(wb + (size_t)(s) * 4096 + (4 + 2 * w + 1) * 512,          \
          WRs(slot) + 1536);                                        \
  }
#define WAITV12 asm volatile("s_waitcnt vmcnt(12)" ::: "memory")
#define WAITV6 asm volatile("s_waitcnt vmcnt(6)" ::: "memory")
#define WAITV0 asm volatile("s_waitcnt vmcnt(0)" ::: "memory")

#define COMPUTE(slot)                                                       \
  {                                                                         \
    const f4 xa0 = *(const f4*)&XRs(slot)[lane * 4];                        \
    const f4 xa1 = *(const f4*)&XRs(slot)[256 + lane * 4];                  \
    h8 ah, al;                                                              \
    const float xf[8] = {xa0[0], xa0[1], xa0[2], xa0[3],                    \
                         xa1[0], xa1[1], xa1[2], xa1[3]};                   \
    _Pragma("unroll") for (int j = 0; j < 8; j++) {                         \
      const _Float16 hv = (_Float16)xf[j];                                  \
      ah[j] = hv;                                                           \
      al[j] = (_Float16)((xf[j] - (float)hv) * 1024.f);                     \
    }                                                                       \
    _Pragma("unroll") for (int nt = 0; nt < 2; nt++) {                      \
      const h8 bh = *(const h8*)&WRs(slot)[nt * 512 + lane * 8];            \
      const h8 bl = *(const h8*)&WRs(slot)[1024 + nt * 512 + lane * 8];     \
      acc1[nt] = __builtin_amdgcn_mfma_f32_16x16x32_f16(ah, bh, acc1[nt],   \
                                                        0, 0, 0);           \
      acc2[nt] = __builtin_amdgcn_mfma_f32_16x16x32_f16(al, bh, acc2[nt],   \
                                                        0, 0, 0);           \
      acc2[nt] = __builtin_amdgcn_mfma_f32_16x16x32_f16(ah, bl, acc2[nt],   \
                                                        0, 0, 0);           \
    }                                                                       \
  }

  // prologue: 3 slots staged (2-step lead at first wait)
  STAGE(0, 0);
  STAGE(1, 1);
  STAGE(2, 2);
  for (int g = 0; g < 20; g++) {  // steps 0..59
    const int s = 3 * g;
    WAITV12;
    COMPUTE(0);
    STAGE(0, s + 3);
    WAITV12;
    COMPUTE(1);
    STAGE(1, s + 4);
    WAITV12;
    COMPUTE(2);
    STAGE(2, s + 5);
  }
  // tail: steps 60..63 (62 staged; 63 still to stage)
  WAITV12;
  COMPUTE(0);          // step 60
  STAGE(0, 63);
  WAITV12;
  COMPUTE(1);          // step 61
  WAITV6;
  COMPUTE(2);          // step 62
  WAITV0;
  COMPUTE(0);          // step 63

  // epilogue: combine expert halves via LDS (ring memory is dead now)
  __syncthreads();
  float* slog = (float*)LB;  // [16][65]
  const int cg = lane >> 4, ci = lane & 15;
#pragma unroll
  for (int nt = 0; nt < 2; nt++)
#pragma unroll
    for (int r = 0; r < 4; r++) {
      const float v =
          (acc1[nt][r] + acc2[nt][r] * 0.0009765625f) * 0.0009765625f;
      slog[(cg * 4 + r) * 65 + (2 * w + nt) * 16 + ci] = v;
    }
  __syncthreads();

  // ---- softmax / top2 / hist / z tail (8 tokens per wave) ----
  float z_acc = 0.f;
  for (int tt = 0; tt < 8; tt++) {
    const int tloc = w * 8 + tt;
    const int n = m0 + tloc;
    const float v = slog[tloc * 65 + lane];
    z_acc += v * v;
    float mx = v;
#pragma unroll
    for (int off = 32; off; off >>= 1) mx = fmaxf(mx, __shfl_xor(mx, off));
    const float p = __expf(v - mx);
    float ssum = p;
#pragma unroll
    for (int off = 32; off; off >>= 1) ssum += __shfl_xor(ssum, off);
    const float rw = p / ssum;
    rw_out[(size_t)n * N_EXP + lane] = rw;

    const unsigned long long b1 = __ballot(v == mx);
    const int i1 = __builtin_ctzll(b1);
    float v2 = (lane == i1) ? -INFINITY : v;
#pragma unroll
    for (int off = 32; off; off >>= 1) v2 = fmaxf(v2, __shfl_xor(v2, off));
    const unsigned long long b2 = __ballot(v == v2) & ~(1ull << i1);
    const int i2 = __builtin_ctzll(b2);
    const float rw1 = __shfl(rw, i1);
    const float rw2 = __shfl(rw, i2);
    if (lane == 0) {
      const float denom = rw1 + rw2 + 1e-8f;
      top12[n] = make_int2(i1, i2);
      wts[n] = make_float2(rw1 / denom, rw2 / denom);
      atomicAdd(&histR[(rep * N_EXP + i1) * 16], 1);
    }
  }
#pragma unroll
  for (int off = 32; off; off >>= 1) z_acc += __shfl_xor(z_acc, off);
  if (lane == 0) atomicAdd(&zR[rep * 16], z_acc);
}

// ---------------- K3: wave-per-token dispatch mask + counts -----------------
__global__ __launch_bounds__(256) void k3_dispatch(
    const int2* __restrict__ top12, const float2* __restrict__ wts,
    const int* __restrict__ histR, float* __restrict__ mask_out,
    float* __restrict__ cntR) {
  const int lane = threadIdx.x & 63;
  const int wid = threadIdx.x >> 6;
  const int n = blockIdx.x * 4 + wid;
  const int rep = blockIdx.x & (NREP - 1);

  const int2 ij = top12[n];
  const float2 w = wts[n];
  int h = 0;
#pragma unroll
  for (int r = 0; r < NREP; r++) h += histR[(r * N_EXP + ij.y) * 16];
  const bool allowed = h < CAPACITY;
  const float ssum = w.x + (allowed ? w.y : 0.f);
  const float inv = 1.f / (ssum + 1e-8f);
  float val = 0.f;
  if (lane == ij.x) val = w.x * inv;
  else if (allowed && lane == ij.y) val = w.y * inv;
  mask_out[(size_t)n * N_EXP + lane] = val;
  if (val != 0.f) atomicAdd(&cntR[(rep * N_EXP + lane) * 16], val);
}

// ---------------- K4: scalar loss -------------------------------------------
__global__ void k4_loss(const float* __restrict__ cntR,
                        const float* __restrict__ zR,
                        float* __restrict__ loss_out) {
  const int lane = threadIdx.x;
  float c = 0.f;
#pragma unroll
  for (int r = 0; r < NREP; r++) c += cntR[(r * N_EXP + lane) * 16];
  const float d = (c - 512.0f) * (1.0f / 16384.0f);
  float v = d * d;
#pragma unroll
  for (int off = 32; off; off >>= 1) v += __shfl_xor(v, off);
  if (lane == 0) {
    float z = 0.f;
#pragma unroll
    for (int r = 0; r < NREP; r++) z += zR[r * 16];
    const float lb = v * (1.0f / 64.0f);
    loss_out[0] = 0.001f * (z * (1.0f / (16384.0f * 64.0f))) + 0.001f * lb;
  }
}

extern "C" void kernel_launch(void* const* d_in, const int* in_sizes, int n_in,
                              void* d_out, int out_size, void* d_ws,
                              size_t ws_size, hipStream_t stream) {
  const float* x = (const float*)d_in[0];
  const float* W = (const float*)d_in[1];
  float* out = (float*)d_out;
  float* rw_out = out;
  float* mask_out = out + (size_t)N_TOK * N_EXP;
  float* loss_out = out + 2 * (size_t)N_TOK * N_EXP;

  char* ws = (char*)d_ws;
  int* histR = (int*)ws;                    // 32 KB
  float* cntR = (float*)(ws + 32768);       // 32 KB
  float* zR = (float*)(ws + 65536);         // 512 B
  int2* top12 = (int2*)(ws + 131072);       // 128 KB
  float2* wts = (float2*)(ws + 262144);     // 128 KB
  _Float16* WT = (_Float16*)(ws + 393216);  // 512 KB (B-frag chunks)

  hipMemsetAsync(histR, 0, 65536 + 512, stream);
  k0_cvtw<<<128, 256, 0, stream>>>(W, WT);
  k12_gemm_softmax<<<1024, 128, 0, stream>>>(x, WT, rw_out, top12, wts, histR,
                                             zR);
  k3_dispatch<<<N_TOK / 4, 256, 0, stream>>>(top12, wts, histR, mask_out,
                                             cntR);
  k4_loss<<<1, 64, 0, stream>>>(cntR, zR, loss_out);
}

// Round 11
// 221.546 us; speedup vs baseline: 1.0824x; 1.0824x over previous
//
#include <hip/hip_runtime.h>
#include <math.h>

#define N_TOK 16384
#define D_MODEL 2048
#define N_EXP 64
#define CAPACITY 640
#define NREP 8
#define NSTEP 64  // K steps of 32

typedef __attribute__((ext_vector_type(8))) _Float16 h8;
typedef __attribute__((ext_vector_type(4))) float f4;

#define AS1 __attribute__((address_space(1)))
#define AS3 __attribute__((address_space(3)))
__device__ __forceinline__ void gld16(const void* g, void* l) {
  __builtin_amdgcn_global_load_lds((const AS1 void*)g, (AS3 void*)l, 16, 0, 0);
}

// ---------------- K0: W -> B-frag 1KB chunks, fp16 hi/lo (W' = W*2^10) ------
// chunk c = s*8 + part*4 + nt  (s = k/32, part: 0=hi 1=lo, nt = expert/16).
// lane l of chunk c: e = nt*16 + (l&15), k = s*32 + (l>>4)*8, 8 halves.
__global__ __launch_bounds__(256) void k0_cvtw(const float* __restrict__ W,
                                               _Float16* __restrict__ WT) {
  const int lane = threadIdx.x & 63;
  const int c = blockIdx.x * 4 + (threadIdx.x >> 6);  // 0..511
  const int s = c >> 3, q = c & 7;
  const int part = q >> 2, nt = q & 3;
  const int e = nt * 16 + (lane & 15);
  const int k = s * 32 + (lane >> 4) * 8;
  const float* src = W + (size_t)e * D_MODEL + k;
  const float4 a = *(const float4*)src;
  const float4 b = *(const float4*)(src + 4);
  const float f[8] = {a.x, a.y, a.z, a.w, b.x, b.y, b.z, b.w};
  h8 out;
#pragma unroll
  for (int j = 0; j < 8; j++) {
    const float sc = f[j] * 1024.f;
    const _Float16 h = (_Float16)sc;
    out[j] = part ? (_Float16)((sc - (float)h) * 1024.f) : h;
  }
  *(h8*)(WT + (size_t)c * 512 + lane * 8) = out;
}

// ---------------- K12: shared-W counted-vmcnt ring GEMM + softmax -----------
// 256 blocks x 256 thr (4 waves); block = 64 tokens. Wave w = 16 distinct
// tokens x 64 experts. W staged ONCE per block (each wave DMAs 2 of 8 chunks
// per step); x wave-private. 4-slot LDS ring (16 KB/slot: x 8KB + W 8KB),
// raw s_barrier + vmcnt(8) per step (never 0 in loop) -> deep pipeline AND
// minimal staged bytes (262 MB chip-wide vs 786 MB in round 10).
__global__ __launch_bounds__(256, 1) void k12_gemm_softmax(
    const float* __restrict__ x, const _Float16* __restrict__ WT,
    float* __restrict__ rw_out, int2* __restrict__ top12,
    float2* __restrict__ wts, int* __restrict__ histR,
    float* __restrict__ zR) {
  __shared__ __align__(16) char LB[65536];  // 4 slots x 16 KB

  const int t = threadIdx.x;
  const int lane = t & 63;
  const int w = t >> 6;
  const int m0 = blockIdx.x * 64;
  const int m0w = m0 + w * 16;
  const int rep = blockIdx.x & (NREP - 1);

  // slot layout: [0,8K): x (wave w at w*2KB); [8K,16K): W chunks q*1KB
#define XSL(slot) ((float*)(LB + (slot) * 16384 + w * 2048))
#define WSL(slot) ((_Float16*)(LB + (slot) * 16384 + 8192))

  // per-lane sources in fragment layout
  const float* xb = x + (size_t)(m0w + (lane & 15)) * D_MODEL + (lane >> 4) * 8;
  const _Float16* wb = WT + lane * 8;

  f4 acc1[4], acc2[4];
#pragma unroll
  for (int i = 0; i < 4; i++) {
    acc1[i] = (f4)(0.f);
    acc2[i] = (f4)(0.f);
  }

#define STAGE(slot, s)                                                  \
  {                                                                     \
    gld16(xb + (s) * 32, XSL(slot));                                    \
    gld16(xb + (s) * 32 + 4, XSL(slot) + 256);                          \
    gld16(wb + (size_t)(s) * 4096 + (2 * w) * 512,                      \
          WSL(slot) + (2 * w) * 512);                                   \
    gld16(wb + (size_t)(s) * 4096 + (2 * w + 1) * 512,                  \
          WSL(slot) + (2 * w + 1) * 512);                               \
  }
#define WAITV8 asm volatile("s_waitcnt vmcnt(8)" ::: "memory")
#define WAITV4 asm volatile("s_waitcnt vmcnt(4)" ::: "memory")
#define WAITV0 asm volatile("s_waitcnt vmcnt(0)" ::: "memory")
#define BAR __builtin_amdgcn_s_barrier()

#define COMPUTE(slot)                                                       \
  {                                                                         \
    const f4 xa0 = *(const f4*)&XSL(slot)[lane * 4];                        \
    const f4 xa1 = *(const f4*)&XSL(slot)[256 + lane * 4];                  \
    h8 ah, al;                                                              \
    const float xf[8] = {xa0[0], xa0[1], xa0[2], xa0[3],                    \
                         xa1[0], xa1[1], xa1[2], xa1[3]};                   \
    _Pragma("unroll") for (int j = 0; j < 8; j++) {                         \
      const _Float16 hv = (_Float16)xf[j];                                  \
      ah[j] = hv;                                                           \
      al[j] = (_Float16)((xf[j] - (float)hv) * 1024.f);                     \
    }                                                                       \
    _Pragma("unroll") for (int nt = 0; nt < 4; nt++) {                      \
      const h8 bh = *(const h8*)&WSL(slot)[nt * 512 + lane * 8];            \
      const h8 bl = *(const h8*)&WSL(slot)[(4 + nt) * 512 + lane * 8];      \
      acc1[nt] = __builtin_amdgcn_mfma_f32_16x16x32_f16(ah, bh, acc1[nt],   \
                                                        0, 0, 0);           \
      acc2[nt] = __builtin_amdgcn_mfma_f32_16x16x32_f16(al, bh, acc2[nt],   \
                                                        0, 0, 0);           \
      acc2[nt] = __builtin_amdgcn_mfma_f32_16x16x32_f16(ah, bl, acc2[nt],   \
                                                        0, 0, 0);           \
    }                                                                       \
  }
  // step s: own step-s loads done (vmcnt<=8) -> barrier (all waves' done,
  // and all waves finished compute(s-1)) -> stage(s+3) into slot (s-1)%4
  // (now free) -> compute(s). Outstanding stays 12; never drains in loop.
#define STEP(slot, stslot, s) \
  {                           \
    WAITV8;                   \
    BAR;                      \
    STAGE(stslot, (s) + 3);   \
    COMPUTE(slot);            \
  }

  // prologue: stage steps 0..2 -> 12 outstanding
  STAGE(0, 0);
  STAGE(1, 1);
  STAGE(2, 2);
  for (int g = 0; g < 15; g++) {  // steps 0..59
    const int s = 4 * g;
    STEP(0, 3, s);
    STEP(1, 0, s + 1);
    STEP(2, 1, s + 2);
    STEP(3, 2, s + 3);
  }
  STEP(0, 3, 60);  // step 60, stages step 63
  WAITV8;
  BAR;
  COMPUTE(1);  // step 61
  WAITV4;
  BAR;
  COMPUTE(2);  // step 62
  WAITV0;
  BAR;
  COMPUTE(3);  // step 63

  __syncthreads();  // ring dead everywhere before slog aliasing

  // epilogue into wave-private slog region (slot w area, now free)
  float* slog = (float*)(LB + w * 16384);  // [16][65] = 4160 B
  const int cg = lane >> 4, ci = lane & 15;
#pragma unroll
  for (int nt = 0; nt < 4; nt++)
#pragma unroll
    for (int r = 0; r < 4; r++) {
      const float v =
          (acc1[nt][r] + acc2[nt][r] * 0.0009765625f) * 0.0009765625f;
      slog[(cg * 4 + r) * 65 + nt * 16 + ci] = v;
    }

  // ---- softmax / top2 / hist / z tail (16 tokens, wave-local) ----
  float z_acc = 0.f;
  for (int tt = 0; tt < 16; tt++) {
    const int n = m0w + tt;
    const float v = slog[tt * 65 + lane];
    z_acc += v * v;
    float mx = v;
#pragma unroll
    for (int off = 32; off; off >>= 1) mx = fmaxf(mx, __shfl_xor(mx, off));
    const float p = __expf(v - mx);
    float ssum = p;
#pragma unroll
    for (int off = 32; off; off >>= 1) ssum += __shfl_xor(ssum, off);
    const float rw = p / ssum;
    rw_out[(size_t)n * N_EXP + lane] = rw;

    const unsigned long long b1 = __ballot(v == mx);
    const int i1 = __builtin_ctzll(b1);
    float v2 = (lane == i1) ? -INFINITY : v;
#pragma unroll
    for (int off = 32; off; off >>= 1) v2 = fmaxf(v2, __shfl_xor(v2, off));
    const unsigned long long b2 = __ballot(v == v2) & ~(1ull << i1);
    const int i2 = __builtin_ctzll(b2);
    const float rw1 = __shfl(rw, i1);
    const float rw2 = __shfl(rw, i2);
    if (lane == 0) {
      const float denom = rw1 + rw2 + 1e-8f;
      top12[n] = make_int2(i1, i2);
      wts[n] = make_float2(rw1 / denom, rw2 / denom);
      atomicAdd(&histR[(rep * N_EXP + i1) * 16], 1);
    }
  }
#pragma unroll
  for (int off = 32; off; off >>= 1) z_acc += __shfl_xor(z_acc, off);
  if (lane == 0) atomicAdd(&zR[rep * 16], z_acc);
}

// ---------------- K3: wave-per-token dispatch mask + counts -----------------
__global__ __launch_bounds__(256) void k3_dispatch(
    const int2* __restrict__ top12, const float2* __restrict__ wts,
    const int* __restrict__ histR, float* __restrict__ mask_out,
    float* __restrict__ cntR) {
  const int lane = threadIdx.x & 63;
  const int wid = threadIdx.x >> 6;
  const int n = blockIdx.x * 4 + wid;
  const int rep = blockIdx.x & (NREP - 1);

  const int2 ij = top12[n];
  const float2 w = wts[n];
  int h = 0;
#pragma unroll
  for (int r = 0; r < NREP; r++) h += histR[(r * N_EXP + ij.y) * 16];
  const bool allowed = h < CAPACITY;
  const float ssum = w.x + (allowed ? w.y : 0.f);
  const float inv = 1.f / (ssum + 1e-8f);
  float val = 0.f;
  if (lane == ij.x) val = w.x * inv;
  else if (allowed && lane == ij.y) val = w.y * inv;
  mask_out[(size_t)n * N_EXP + lane] = val;
  if (val != 0.f) atomicAdd(&cntR[(rep * N_EXP + lane) * 16], val);
}

// ---------------- K4: scalar loss -------------------------------------------
__global__ void k4_loss(const float* __restrict__ cntR,
                        const float* __restrict__ zR,
                        float* __restrict__ loss_out) {
  const int lane = threadIdx.x;
  float c = 0.f;
#pragma unroll
  for (int r = 0; r < NREP; r++) c += cntR[(r * N_EXP + lane) * 16];
  const float d = (c - 512.0f) * (1.0f / 16384.0f);
  float v = d * d;
#pragma unroll
  for (int off = 32; off; off >>= 1) v += __shfl_xor(v, off);
  if (lane == 0) {
    float z = 0.f;
#pragma unroll
    for (int r = 0; r < NREP; r++) z += zR[r * 16];
    const float lb = v * (1.0f / 64.0f);
    loss_out[0] = 0.001f * (z * (1.0f / (16384.0f * 64.0f))) + 0.001f * lb;
  }
}

extern "C" void kernel_launch(void* const* d_in, const int* in_sizes, int n_in,
                              void* d_out, int out_size, void* d_ws,
                              size_t ws_size, hipStream_t stream) {
  const float* x = (const float*)d_in[0];
  const float* W = (const float*)d_in[1];
  float* out = (float*)d_out;
  float* rw_out = out;
  float* mask_out = out + (size_t)N_TOK * N_EXP;
  float* loss_out = out + 2 * (size_t)N_TOK * N_EXP;

  char* ws = (char*)d_ws;
  int* histR = (int*)ws;                    // 32 KB
  float* cntR = (float*)(ws + 32768);       // 32 KB
  float* zR = (float*)(ws + 65536);         // 512 B
  int2* top12 = (int2*)(ws + 131072);       // 128 KB
  float2* wts = (float2*)(ws + 262144);     // 128 KB
  _Float16* WT = (_Float16*)(ws + 393216);  // 512 KB (B-frag chunks)

  hipMemsetAsync(histR, 0, 65536 + 512, stream);
  k0_cvtw<<<128, 256, 0, stream>>>(W, WT);
  k12_gemm_softmax<<<N_TOK / 64, 256, 0, stream>>>(x, WT, rw_out, top12, wts,
                                                   histR, zR);
  k3_dispatch<<<N_TOK / 4, 256, 0, stream>>>(top12, wts, histR, mask_out,
                                             cntR);
  k4_loss<<<1, 64, 0, stream>>>(cntR, zR, loss_out);
}